// Round 12
// baseline (1119.683 us; speedup 1.0000x reference)
//
#include <hip/hip_runtime.h>
#include <hip/hip_fp16.h>
#include <cstdio>

typedef _Float16 f16;
typedef _Float16 f16x8 __attribute__((ext_vector_type(8)));
typedef _Float16 f16x4 __attribute__((ext_vector_type(4)));
typedef float f32x4 __attribute__((ext_vector_type(4)));

#define DI __device__ __forceinline__

DI void gload_lds16(const void* g, void* l) {
  __builtin_amdgcn_global_load_lds(
      (const __attribute__((address_space(1))) void*)g,
      (__attribute__((address_space(3))) void*)l, 16, 0, 0);
}

// XCD-aware block swizzle (bijective when gridDim.x % 8 == 0) [T1]
DI int xcd_swz() {
  int nwg = gridDim.x, bid = blockIdx.x;
  if ((nwg & 7) == 0) bid = (bid & 7) * (nwg >> 3) + (bid >> 3);
  return bid;
}

// ---------------- cast f32 -> f16, 4 elems/thread ----------------
__global__ void k_cast(const float* __restrict__ in, f16* __restrict__ out, int n4) {
  int i = blockIdx.x * blockDim.x + threadIdx.x;
  if (i >= n4) return;
  float4 v = ((const float4*)in)[i];
  f16x4 o;
  o[0] = (f16)v.x; o[1] = (f16)v.y; o[2] = (f16)v.z; o[3] = (f16)v.w;
  ((f16x4*)out)[i] = o;
}

// ---------------- RoPE in-place on q,k regions of qkv ----------------
__global__ void k_rope(f16* __restrict__ qkv) {
  int gid = blockIdx.x * blockDim.x + threadIdx.x;  // 16384*512
  int tt = gid >> 9, j = gid & 511;
  int t = tt & 8191;
  float invf = powf(10000.0f, -(float)j * (1.0f / 512.0f));
  float a = (float)t * invf;
  float s, c;
  sincosf(a, &s, &c);
  f16* row = qkv + (size_t)tt * 3072;
  float q0 = (float)row[j], q1 = (float)row[j + 512];
  row[j]       = (f16)(q0 * c - q1 * s);
  row[j + 512] = (f16)(q1 * c + q0 * s);
  float k0 = (float)row[1024 + j], k1 = (float)row[1536 + j];
  row[1024 + j] = (f16)(k0 * c - k1 * s);
  row[1536 + j] = (f16)(k1 * c + k0 * s);
}

// ---------------- V transpose: qkv[:,2048:3072] -> vt[b][d][t] ----------------
__global__ __launch_bounds__(256) void k_transpose(const f16* __restrict__ qkv, f16* __restrict__ vt) {
  __shared__ f16 tile[64][72];
  int bid = blockIdx.x;            // 2 * 128 * 16
  int b = bid >> 11;
  int rem = bid & 2047;
  int tb = (rem >> 4) * 64;        // token base
  int db = (rem & 15) * 64;        // d base
  int tid = threadIdx.x;
  int r = tid >> 2, c0 = (tid & 3) * 16;
  const f16* src = qkv + (size_t)(b * 8192 + tb + r) * 3072 + 2048 + db + c0;
  #pragma unroll
  for (int ii = 0; ii < 16; ++ii) tile[r][c0 + ii] = src[ii];
  __syncthreads();
  f16* dst = vt + (size_t)b * 1024 * 8192 + (size_t)(db + r) * 8192 + tb + c0;
  #pragma unroll
  for (int ii = 0; ii < 16; ++ii) dst[ii] = tile[c0 + ii][r];
}

// ---------------- chunk softmax, wave-per-row, float4, IN-PLACE S->P ----------
// chunk [q0,q1): R = q1-q0 rows per batch; S is [2R][q1] f32, batch stride R rows.
__global__ __launch_bounds__(256)
void k_softmax_c(float* __restrict__ S, int q0, int q1) {
  int R = q1 - q0;
  int row = blockIdx.x * 4 + (threadIdx.x >> 6);  // 0..2R-1
  int lane = threadIdx.x & 63;
  int b = (row >= R) ? 1 : 0;
  int qloc = row - b * R;
  int qg = q0 + qloc;
  float* Srow = S + (size_t)row * q1;
  int nvalid = qg + 1;

  float m = -INFINITY, ssum = 0.f;
  for (int kk = lane * 4; kk < nvalid; kk += 256) {
    float4 v = *(const float4*)(Srow + kk);
    int rem = nvalid - kk;
    if (rem < 4) {
      if (rem < 2) v.y = -INFINITY;
      if (rem < 3) v.z = -INFINITY;
      v.w = -INFINITY;
    }
    float g = fmaxf(fmaxf(v.x, v.y), fmaxf(v.z, v.w));
    if (g > m) { ssum *= __expf(m - g); m = g; }
    ssum += __expf(v.x - m) + __expf(v.y - m) + __expf(v.z - m) + __expf(v.w - m);
  }
  #pragma unroll
  for (int msk = 32; msk >= 1; msk >>= 1) {
    float om = __shfl_xor(m, msk);
    float os = __shfl_xor(ssum, msk);
    float M = fmaxf(m, om);
    float aa = (m > -INFINITY) ? ssum * __expf(m - M) : 0.f;
    float cc = (om > -INFINITY) ? os * __expf(om - M) : 0.f;
    m = M; ssum = aa + cc;
  }
  float rinv = 0.03125f / ssum;  // 1024^-0.5 applied post-softmax (reference quirk)
  int klim = (qg | 127) + 1;     // zero-fill to PV's k-tile boundary
  f16* Prow = (f16*)Srow;
  for (int kk = lane * 4; kk < klim; kk += 256) {
    float4 v = *(const float4*)(Srow + kk);
    asm volatile("" ::: "memory");  // keep f32 load before aliasing f16 store
    f16x4 o;
    o[0] = (f16)((kk     < nvalid) ? __expf(v.x - m) * rinv : 0.f);
    o[1] = (f16)((kk + 1 < nvalid) ? __expf(v.y - m) * rinv : 0.f);
    o[2] = (f16)((kk + 2 < nvalid) ? __expf(v.z - m) * rinv : 0.f);
    o[3] = (f16)((kk + 3 < nvalid) ? __expf(v.w - m) * rinv : 0.f);
    *(f16x4*)(Prow + kk) = o;
  }
}

// ---- shared 128x128xK GEMM: 5-slot pipeline (prefetch-3, counted vmcnt [T4])
// ---- + T2 chunk swizzle: physical 16B-chunk p of row r holds logical chunk
// ---- (p - (r>>1))&3. Writer pre-swizzles the per-lane GLOBAL source (gload_lds
// ---- writes linearly); reader uses pchunk = ((l>>4) + ((l&15)>>1))&3. Turns the
// ---- 8-way ds_read_b128 bank conflict into 2-way (free). [rule 21: both sides]
// MODE 1: qkv = x_h @ w_attn^T + b   -> fp16
// MODE 2: S[2R][q1] = q @ k^T        (chunk [q0,q1), causal block skip) -> fp32
// MODE 3: xo = P @ vt^T              (chunk, P in-place in S, lda=2*q1) -> fp16
// MODE 4: out = o @ w_proj^T + b     -> fp32
template <int MODE>
__global__ __launch_bounds__(256)
void gemm_k(const f16* __restrict__ A, const f16* __restrict__ B,
            void* __restrict__ C, const float* __restrict__ bias, int q0, int q1)
{
  __shared__ __align__(16) f16 As[5 * 4096];   // 5 slots x 128x32 f16 (8 KB) = 40 KB
  __shared__ __align__(16) f16 Bs[5 * 4096];   // 40 KB  (total 80 KB -> 2 blocks/CU)

  const int tid = threadIdx.x;
  const int w = tid >> 6;
  const int l = tid & 63;
  const int wm = w >> 1, wn = w & 1;
  const int bid = xcd_swz();
  const int R = q1 - q0;

  int nk = 0;
  const f16* Abase = nullptr;
  const f16* Bbase = nullptr;
  size_t crow0 = 0, ccol0 = 0, cld = 0;
  const int LDA = (MODE == 2) ? 3072 : (MODE == 3 ? 2 * q1 : 1024);
  const int LDB = (MODE == 2) ? 3072 : (MODE == 3 ? 8192 : 1024);

  if constexpr (MODE == 1) {
    int bm = bid / 24, bn = bid % 24;
    Abase = A + (size_t)bm * 128 * 1024;
    Bbase = B + (size_t)bn * 128 * 1024;
    nk = 32; crow0 = (size_t)bm * 128; ccol0 = (size_t)bn * 128; cld = 3072;
  } else if constexpr (MODE == 2) {
    int nqt = R >> 7, ncb = q1 >> 7;
    int b = bid / (nqt * ncb);
    int rem = bid % (nqt * ncb);
    int qb = rem / ncb, jb = rem % ncb;
    if (jb > (q0 >> 7) + qb) return;   // fully-masked block (block-uniform exit, pre-barrier)
    Abase = A + (size_t)(b * 8192 + q0 + qb * 128) * 3072;
    Bbase = A + (size_t)(b * 8192 + jb * 128) * 3072 + 1024;
    nk = 32;
    crow0 = (size_t)(b * R + qb * 128); ccol0 = (size_t)jb * 128; cld = q1;
  } else if constexpr (MODE == 3) {
    int nqt = R >> 7;
    int b = bid / (nqt * 8);
    int rem = bid % (nqt * 8);
    int qb = rem / 8, nb = rem % 8;
    nk = ((q0 >> 7) + qb + 1) * 4;     // K-steps of 32 over valid k-tiles (>= 4)
    Abase = A + (size_t)(b * R + qb * 128) * 2 * q1;   // P in-place in S
    Bbase = B + (size_t)b * 1024 * 8192 + (size_t)nb * 128 * 8192;
    crow0 = (size_t)(b * 8192 + q0 + qb * 128); ccol0 = (size_t)nb * 128; cld = 1024;
  } else {
    int bm = bid / 8, bn = bid % 8;
    Abase = A + (size_t)bm * 128 * 1024;
    Bbase = B + (size_t)bn * 128 * 1024;
    nk = 32; crow0 = (size_t)bm * 128; ccol0 = (size_t)bn * 128; cld = 1024;
  }

  f32x4 zero = {0.f, 0.f, 0.f, 0.f};
  f32x4 acc[4][4];
  #pragma unroll
  for (int m = 0; m < 4; ++m)
    #pragma unroll
    for (int n = 0; n < 4; ++n) acc[m][n] = zero;

  const int srow = l >> 2;          // staging: 4 lanes per 32-elem row
  // T2 writer-side swizzle: lane l loads LOGICAL chunk ((l&3) - ((l>>3)&3))&3
  // so the linear gload_lds write lands it at physical chunk l&3 of its row.
  const int skoff = (((l & 3) - ((l >> 3) & 3)) & 3) * 8;
  const int lr = l & 15;            // fragment row/col
  // T2 reader-side: physical chunk for logical chunk (l>>4) at row ...+lr
  const int pch = ((l >> 4) + (lr >> 1)) & 3;
  const int rb0 = w * 16;           // stage rows, half 0
  const int rb1 = 64 + w * 16;      // stage rows, half 1

  // hoisted per-lane global staging pointers; tile t adds offset t*32 elems
  const f16* gA0 = Abase + (size_t)(rb0 + srow) * LDA + skoff;
  const f16* gA1 = Abase + (size_t)(rb1 + srow) * LDA + skoff;
  const f16* gB0 = Bbase + (size_t)(rb0 + srow) * LDB + skoff;
  const f16* gB1 = Bbase + (size_t)(rb1 + srow) * LDB + skoff;
  const int ldsA0 = rb0 * 32, ldsA1 = rb1 * 32;   // wave-uniform LDS dest offsets
  const int aoff = (wm * 64 + lr) * 32 + pch * 8;  // fragment-read element offsets
  const int boff = (wn * 64 + lr) * 32 + pch * 8;

#define STAGE(slot, t) do { \
    const size_t _o = (size_t)(t) * 32; \
    f16* _as = As + (slot) * 4096; f16* _bs = Bs + (slot) * 4096; \
    gload_lds16(gA0 + _o, _as + ldsA0); \
    gload_lds16(gA1 + _o, _as + ldsA1); \
    gload_lds16(gB0 + _o, _bs + ldsA0); \
    gload_lds16(gB1 + _o, _bs + ldsA1); } while (0)
#define COMPUTE(slot) do { \
    const f16* pa = As + (slot) * 4096 + aoff; \
    const f16* pb = Bs + (slot) * 4096 + boff; \
    f16x8 av[4], bv[4]; \
    _Pragma("unroll") for (int m = 0; m < 4; ++m) av[m] = *(const f16x8*)(pa + m * 512); \
    _Pragma("unroll") for (int n = 0; n < 4; ++n) bv[n] = *(const f16x8*)(pb + n * 512); \
    _Pragma("unroll") for (int m = 0; m < 4; ++m) \
      _Pragma("unroll") for (int n = 0; n < 4; ++n) \
        acc[m][n] = __builtin_amdgcn_mfma_f32_16x16x32_f16(av[m], bv[n], acc[m][n], 0, 0, 0); \
  } while (0)

  // prologue: stage tiles 0,1,2 into slots 0,1,2 (12 loads in flight); nk >= 4 always
  STAGE(0, 0); STAGE(1, 1); STAGE(2, 2);

  int sc = 3, cc = 0;                // stage slot (i+3)%5, compute slot i%5
  for (int i = 0; i + 3 < nk; ++i) {
    STAGE(sc, i + 3);
    asm volatile("s_waitcnt vmcnt(12)" ::: "memory");  // commit tile i; 3 tiles in flight
    __builtin_amdgcn_s_barrier();
    COMPUTE(cc);
    sc = (sc == 4) ? 0 : sc + 1;
    cc = (cc == 4) ? 0 : cc + 1;
  }
  // tail: 3 iters, no staging; vmcnt counts down exactly (in-order retirement)
  asm volatile("s_waitcnt vmcnt(8)" ::: "memory");
  __builtin_amdgcn_s_barrier();
  COMPUTE(cc); cc = (cc == 4) ? 0 : cc + 1;
  asm volatile("s_waitcnt vmcnt(4)" ::: "memory");
  __builtin_amdgcn_s_barrier();
  COMPUTE(cc); cc = (cc == 4) ? 0 : cc + 1;
  asm volatile("s_waitcnt vmcnt(0)" ::: "memory");
  __builtin_amdgcn_s_barrier();
  COMPUTE(cc);
#undef STAGE
#undef COMPUTE

  const int rg = (l >> 4) * 4;  // C/D: col = lane&15, row = (lane>>4)*4 + reg
  #pragma unroll
  for (int m = 0; m < 4; ++m) {
    #pragma unroll
    for (int n = 0; n < 4; ++n) {
      f32x4 v = acc[m][n];
      size_t coll = ccol0 + wn * 64 + n * 16 + lr;
      #pragma unroll
      for (int r = 0; r < 4; ++r) {
        size_t roww = crow0 + wm * 64 + m * 16 + rg + r;
        if constexpr (MODE == 1) {
          ((f16*)C)[roww * cld + coll] = (f16)(v[r] + bias[coll]);
        } else if constexpr (MODE == 2) {
          ((float*)C)[roww * cld + coll] = v[r];
        } else if constexpr (MODE == 3) {
          ((f16*)C)[roww * cld + coll] = (f16)v[r];
        } else {
          ((float*)C)[roww * cld + coll] = v[r] + bias[coll];
        }
      }
    }
  }
}

extern "C" void kernel_launch(void* const* d_in, const int* in_sizes, int n_in,
                              void* d_out, int out_size, void* d_ws, size_t ws_size,
                              hipStream_t stream) {
  (void)in_sizes; (void)n_in;
  const float* x      = (const float*)d_in[0];
  const float* w_attn = (const float*)d_in[1];
  const float* b_attn = (const float*)d_in[2];
  const float* w_proj = (const float*)d_in[3];
  const float* b_proj = (const float*)d_in[4];
  float* out = (float*)d_out;

  const size_t WS_NEED = 264765440ull;  // 252.5 MiB
  if (ws_size < WS_NEED) {
    fprintf(stderr, "kernel_launch: ws_size=%zu < needed %zu -- skipping launches\n",
            ws_size, WS_NEED);
    hipMemsetAsync(d_out, 0, (size_t)out_size * 4, stream);
    return;
  }

  char* p = (char*)d_ws;
  f16* wA_h = (f16*)p; p += (size_t)3072 * 1024 * 2;       //   6.3 MB
  f16* wP_h = (f16*)p; p += (size_t)1024 * 1024 * 2;       //   2.1 MB
  f16* qkv  = (f16*)p; p += (size_t)16384 * 3072 * 2;      // 100.7 MB
  f16* vt   = (f16*)p; p += (size_t)2 * 1024 * 8192 * 2;   //  33.6 MB
  f16* xo   = (f16*)p; p += (size_t)16384 * 1024 * 2;      //  33.6 MB (x_h, then o_h)
  float* S  = (float*)p; p += (size_t)2 * 3328 * 3328 * 4; //  88.6 MB (scores; P in-place)
  // total 264,765,440 bytes

  k_cast<<<16384, 256, 0, stream>>>(x, xo, 4194304);
  k_cast<<<3072, 256, 0, stream>>>(w_attn, wA_h, 786432);
  k_cast<<<1024, 256, 0, stream>>>(w_proj, wP_h, 262144);
  hipLaunchKernelGGL(HIP_KERNEL_NAME(gemm_k<1>), dim3(3072), dim3(256), 0, stream,
                     xo, wA_h, (void*)qkv, b_attn, 0, 8192);
  k_rope<<<32768, 256, 0, stream>>>(qkv);
  k_transpose<<<4096, 256, 0, stream>>>(qkv, vt);

  // 4 variable chunks equalizing S footprint: grids stay large (no split-K needed)
  const int Q0[4] = {0, 3328, 5376, 6912};
  const int Q1[4] = {3328, 5376, 6912, 8192};
  for (int c = 0; c < 4; ++c) {
    int q0 = Q0[c], q1 = Q1[c], R = q1 - q0;
    int nqt = R >> 7, ncb = q1 >> 7;
    hipLaunchKernelGGL(HIP_KERNEL_NAME(gemm_k<2>), dim3(2 * nqt * ncb), dim3(256), 0, stream,
                       qkv, (const f16*)nullptr, (void*)S, (const float*)nullptr, q0, q1);
    k_softmax_c<<<R / 2, 256, 0, stream>>>(S, q0, q1);
    hipLaunchKernelGGL(HIP_KERNEL_NAME(gemm_k<3>), dim3(2 * nqt * 8), dim3(256), 0, stream,
                       (const f16*)S, vt, (void*)xo, (const float*)nullptr, q0, q1);
  }
  hipLaunchKernelGGL(HIP_KERNEL_NAME(gemm_k<4>), dim3(1024), dim3(256), 0, stream,
                     xo, wP_h, (void*)out, b_proj, 0, 8192);
}

// Round 13
// 1052.605 us; speedup vs baseline: 1.0637x; 1.0637x over previous
//
#include <hip/hip_runtime.h>
#include <hip/hip_fp16.h>
#include <cstdio>

typedef _Float16 f16;
typedef _Float16 f16x8 __attribute__((ext_vector_type(8)));
typedef _Float16 f16x4 __attribute__((ext_vector_type(4)));
typedef float f32x4 __attribute__((ext_vector_type(4)));

#define DI __device__ __forceinline__

DI void gload_lds16(const void* g, void* l) {
  __builtin_amdgcn_global_load_lds(
      (const __attribute__((address_space(1))) void*)g,
      (__attribute__((address_space(3))) void*)l, 16, 0, 0);
}

// XCD-aware block swizzle (bijective when gridDim.x % 8 == 0) [T1]
DI int xcd_swz() {
  int nwg = gridDim.x, bid = blockIdx.x;
  if ((nwg & 7) == 0) bid = (bid & 7) * (nwg >> 3) + (bid >> 3);
  return bid;
}

// ---------------- cast f32 -> f16, 4 elems/thread ----------------
__global__ void k_cast(const float* __restrict__ in, f16* __restrict__ out, int n4) {
  int i = blockIdx.x * blockDim.x + threadIdx.x;
  if (i >= n4) return;
  float4 v = ((const float4*)in)[i];
  f16x4 o;
  o[0] = (f16)v.x; o[1] = (f16)v.y; o[2] = (f16)v.z; o[3] = (f16)v.w;
  ((f16x4*)out)[i] = o;
}

// ---------------- RoPE in-place, vectorized: 8 pairs/thread ----------------
__global__ void k_rope(f16* __restrict__ qkv) {
  int gid = blockIdx.x * blockDim.x + threadIdx.x;  // 16384 * 64
  int tt = gid >> 6, j0 = (gid & 63) * 8;
  int t = tt & 8191;
  f16* row = qkv + (size_t)tt * 3072;
  f16x8 qa = *(f16x8*)(row + j0),        qb = *(f16x8*)(row + 512 + j0);
  f16x8 ka = *(f16x8*)(row + 1024 + j0), kb = *(f16x8*)(row + 1536 + j0);
  #pragma unroll
  for (int u = 0; u < 8; ++u) {
    int j = j0 + u;
    float invf = powf(10000.0f, -(float)j * (1.0f / 512.0f));
    float s, c;
    sincosf((float)t * invf, &s, &c);
    float q0v = (float)qa[u], q1v = (float)qb[u];
    qa[u] = (f16)(q0v * c - q1v * s); qb[u] = (f16)(q1v * c + q0v * s);
    float k0v = (float)ka[u], k1v = (float)kb[u];
    ka[u] = (f16)(k0v * c - k1v * s); kb[u] = (f16)(k1v * c + k0v * s);
  }
  *(f16x8*)(row + j0) = qa;        *(f16x8*)(row + 512 + j0) = qb;
  *(f16x8*)(row + 1024 + j0) = ka; *(f16x8*)(row + 1536 + j0) = kb;
}

// ---------------- V transpose: qkv[:,2048:3072] -> vt[b][d][t] ----------------
__global__ __launch_bounds__(256) void k_transpose(const f16* __restrict__ qkv, f16* __restrict__ vt) {
  __shared__ f16 tile[64][72];
  int bid = blockIdx.x;            // 2 * 128 * 16
  int b = bid >> 11;
  int rem = bid & 2047;
  int tb = (rem >> 4) * 64;        // token base
  int db = (rem & 15) * 64;        // d base
  int tid = threadIdx.x;
  int r = tid >> 2, c0 = (tid & 3) * 16;
  const f16* src = qkv + (size_t)(b * 8192 + tb + r) * 3072 + 2048 + db + c0;
  #pragma unroll
  for (int ii = 0; ii < 16; ++ii) tile[r][c0 + ii] = src[ii];
  __syncthreads();
  f16* dst = vt + (size_t)b * 1024 * 8192 + (size_t)(db + r) * 8192 + tb + c0;
  #pragma unroll
  for (int ii = 0; ii < 16; ++ii) dst[ii] = tile[c0 + ii][r];
}

// ---------------- chunk softmax: pass1 from Pstat partials, pass2 in-place S->P --
// Pstat[srow*64 + jb] = (block row max, block row sumexp) from gemm_pp<2> epilogue.
__global__ __launch_bounds__(256)
void k_softmax_c(float* __restrict__ S, const float2* __restrict__ Pstat, int q0, int q1) {
  int R = q1 - q0;
  int row = blockIdx.x * 4 + (threadIdx.x >> 6);  // 0..2R-1
  int lane = threadIdx.x & 63;
  int b = (row >= R) ? 1 : 0;
  int qloc = row - b * R;
  int qg = q0 + qloc;
  float* Srow = S + (size_t)row * q1;
  int nvalid = qg + 1;
  int djb = qg >> 7;                // last valid 128-col block for this row

  // pass 1: merge per-block partials (<=64 of them) with a 64-lane butterfly
  float2 st = make_float2(-INFINITY, 0.f);
  if (lane <= djb) st = Pstat[(size_t)row * 64 + lane];
  float m = st.x;
  #pragma unroll
  for (int msk = 32; msk >= 1; msk >>= 1) m = fmaxf(m, __shfl_xor(m, msk));
  float contrib = (lane <= djb) ? st.y * __expf(st.x - m) : 0.f;
  #pragma unroll
  for (int msk = 32; msk >= 1; msk >>= 1) contrib += __shfl_xor(contrib, msk);
  float ssum = contrib;

  float rinv = 0.03125f / ssum;  // 1024^-0.5 applied post-softmax (reference quirk)
  int klim = (qg | 127) + 1;     // zero-fill to PV's k-tile boundary
  f16* Prow = (f16*)Srow;
  for (int kk = lane * 4; kk < klim; kk += 256) {
    float4 v = *(const float4*)(Srow + kk);
    asm volatile("" ::: "memory");  // keep f32 load before aliasing f16 store
    f16x4 o;
    o[0] = (f16)((kk     < nvalid) ? __expf(v.x - m) * rinv : 0.f);
    o[1] = (f16)((kk + 1 < nvalid) ? __expf(v.y - m) * rinv : 0.f);
    o[2] = (f16)((kk + 2 < nvalid) ? __expf(v.z - m) * rinv : 0.f);
    o[3] = (f16)((kk + 3 < nvalid) ? __expf(v.w - m) * rinv : 0.f);
    *(f16x4*)(Prow + kk) = o;
  }
}

// ==== gemm_pipe: 5-slot pipeline, prefetch-3, counted vmcnt [T4], LINEAR lds ====
// MODE 1: qkv = x_h @ w_attn^T + b  (L2 super-tiled 8bm x 4bn)  -> fp16
// MODE 4: out = o @ w_proj^T + b                                -> fp32
template <int MODE>
__global__ __launch_bounds__(256)
void gemm_pipe(const f16* __restrict__ A, const f16* __restrict__ B,
               void* __restrict__ C, const float* __restrict__ bias)
{
  __shared__ __align__(16) f16 As[5 * 4096];   // 5 slots x 128x32 f16 = 40 KB
  __shared__ __align__(16) f16 Bs[5 * 4096];   // 40 KB

  const int tid = threadIdx.x;
  const int w = tid >> 6;
  const int l = tid & 63;
  const int wm = w >> 1, wn = w & 1;
  const int bid = xcd_swz();

  int bm, bn;
  if constexpr (MODE == 1) {
    // L2 super-tiles: 32 blocks = 8 bm x 4 bn (A 2MB + B 1MB = 3MB <= 4MB L2)
    int grp = bid >> 5, off = bid & 31;
    bm = (grp / 6) * 8 + (off >> 2);
    bn = (grp % 6) * 4 + (off & 3);
  } else {
    bm = bid / 8; bn = bid % 8;
  }
  const int nk = 32;
  const f16* Abase = A + (size_t)bm * 128 * 1024;
  const f16* Bbase = B + (size_t)bn * 128 * 1024;
  const size_t crow0 = (size_t)bm * 128, ccol0 = (size_t)bn * 128;
  const size_t cld = (MODE == 1) ? 3072 : 1024;

  f32x4 zero = {0.f, 0.f, 0.f, 0.f};
  f32x4 acc[4][4];
  #pragma unroll
  for (int m = 0; m < 4; ++m)
    #pragma unroll
    for (int n = 0; n < 4; ++n) acc[m][n] = zero;

  const int srow = l >> 2;
  const int skoff = (l & 3) * 8;       // linear (r12's rotation reverted)
  const int lr = l & 15;
  const int kg = (l >> 4) * 8;
  const int rb0 = w * 16, rb1 = 64 + w * 16;

  const f16* gA0 = Abase + (size_t)(rb0 + srow) * 1024 + skoff;
  const f16* gA1 = Abase + (size_t)(rb1 + srow) * 1024 + skoff;
  const f16* gB0 = Bbase + (size_t)(rb0 + srow) * 1024 + skoff;
  const f16* gB1 = Bbase + (size_t)(rb1 + srow) * 1024 + skoff;
  const int ldsA0 = rb0 * 32, ldsA1 = rb1 * 32;
  const int aoff = (wm * 64 + lr) * 32 + kg;
  const int boff = (wn * 64 + lr) * 32 + kg;

#define STAGE(slot, t) do { \
    const size_t _o = (size_t)(t) * 32; \
    f16* _as = As + (slot) * 4096; f16* _bs = Bs + (slot) * 4096; \
    gload_lds16(gA0 + _o, _as + ldsA0); \
    gload_lds16(gA1 + _o, _as + ldsA1); \
    gload_lds16(gB0 + _o, _bs + ldsA0); \
    gload_lds16(gB1 + _o, _bs + ldsA1); } while (0)
#define COMPUTE(slot) do { \
    const f16* pa = As + (slot) * 4096 + aoff; \
    const f16* pb = Bs + (slot) * 4096 + boff; \
    f16x8 av[4], bv[4]; \
    _Pragma("unroll") for (int m = 0; m < 4; ++m) av[m] = *(const f16x8*)(pa + m * 512); \
    _Pragma("unroll") for (int n = 0; n < 4; ++n) bv[n] = *(const f16x8*)(pb + n * 512); \
    _Pragma("unroll") for (int m = 0; m < 4; ++m) \
      _Pragma("unroll") for (int n = 0; n < 4; ++n) \
        acc[m][n] = __builtin_amdgcn_mfma_f32_16x16x32_f16(av[m], bv[n], acc[m][n], 0, 0, 0); \
  } while (0)

  STAGE(0, 0); STAGE(1, 1); STAGE(2, 2);
  int sc = 3, cc = 0;
  for (int i = 0; i + 3 < nk; ++i) {
    STAGE(sc, i + 3);
    asm volatile("s_waitcnt vmcnt(12)" ::: "memory");
    __builtin_amdgcn_s_barrier();
    COMPUTE(cc);
    sc = (sc == 4) ? 0 : sc + 1;
    cc = (cc == 4) ? 0 : cc + 1;
  }
  asm volatile("s_waitcnt vmcnt(8)" ::: "memory");
  __builtin_amdgcn_s_barrier();
  COMPUTE(cc); cc = (cc == 4) ? 0 : cc + 1;
  asm volatile("s_waitcnt vmcnt(4)" ::: "memory");
  __builtin_amdgcn_s_barrier();
  COMPUTE(cc); cc = (cc == 4) ? 0 : cc + 1;
  asm volatile("s_waitcnt vmcnt(0)" ::: "memory");
  __builtin_amdgcn_s_barrier();
  COMPUTE(cc);
#undef STAGE
#undef COMPUTE

  const int rg = (l >> 4) * 4;
  #pragma unroll
  for (int m = 0; m < 4; ++m) {
    #pragma unroll
    for (int n = 0; n < 4; ++n) {
      f32x4 v = acc[m][n];
      size_t coll = ccol0 + wn * 64 + n * 16 + lr;
      #pragma unroll
      for (int r = 0; r < 4; ++r) {
        size_t roww = crow0 + wm * 64 + m * 16 + rg + r;
        if constexpr (MODE == 1) {
          ((f16*)C)[roww * cld + coll] = (f16)(v[r] + bias[coll]);
        } else {
          ((float*)C)[roww * cld + coll] = v[r] + bias[coll];
        }
      }
    }
  }
}

// ==== gemm_pp: r10 ping-pong engine (2-phase, 32 KB LDS, high occupancy) ====
// MODE 2: S[2R][q1] = q @ k^T  + per-(row,block) (max,sumexp) -> Pstat
// MODE 3: xo = P @ vt^T        (P in-place in S, lda=2*q1)    -> fp16
template <int MODE>
__global__ __launch_bounds__(256)
void gemm_pp(const f16* __restrict__ A, const f16* __restrict__ B,
             void* __restrict__ C, float2* __restrict__ Pstat, int q0, int q1)
{
  __shared__ __align__(16) f16 As0[128 * 32];
  __shared__ __align__(16) f16 As1[128 * 32];
  __shared__ __align__(16) f16 Bs0[128 * 32];
  __shared__ __align__(16) f16 Bs1[128 * 32];

  const int tid = threadIdx.x;
  const int w = tid >> 6;
  const int l = tid & 63;
  const int wm = w >> 1, wn = w & 1;
  const int bid = xcd_swz();
  const int R = q1 - q0;

  int nk = 0, qb2 = 0, jb2 = 0;
  const f16* Abase = nullptr;
  const f16* Bbase = nullptr;
  size_t crow0 = 0, ccol0 = 0, cld = 0;
  const int LDA = (MODE == 2) ? 3072 : 2 * q1;
  const int LDB = (MODE == 2) ? 3072 : 8192;

  if constexpr (MODE == 2) {
    int nqt = R >> 7, ncb = q1 >> 7;
    int b = bid / (nqt * ncb);
    int rem = bid % (nqt * ncb);
    qb2 = rem / ncb; jb2 = rem % ncb;
    if (jb2 > (q0 >> 7) + qb2) return;   // fully-masked (uniform exit, pre-barrier)
    Abase = A + (size_t)(b * 8192 + q0 + qb2 * 128) * 3072;
    Bbase = A + (size_t)(b * 8192 + jb2 * 128) * 3072 + 1024;
    nk = 32;
    crow0 = (size_t)(b * R + qb2 * 128); ccol0 = (size_t)jb2 * 128; cld = q1;
  } else {
    int nqt = R >> 7;
    int b = bid / (nqt * 8);
    int rem = bid % (nqt * 8);
    int qb = rem / 8, nb = rem % 8;
    nk = ((q0 >> 7) + qb + 1) * 4;       // even
    Abase = A + (size_t)(b * R + qb * 128) * 2 * q1;   // P in-place in S
    Bbase = B + (size_t)b * 1024 * 8192 + (size_t)nb * 128 * 8192;
    crow0 = (size_t)(b * 8192 + q0 + qb * 128); ccol0 = (size_t)nb * 128; cld = 1024;
  }

  f32x4 zero = {0.f, 0.f, 0.f, 0.f};
  f32x4 acc[4][4];
  #pragma unroll
  for (int m = 0; m < 4; ++m)
    #pragma unroll
    for (int n = 0; n < 4; ++n) acc[m][n] = zero;

  const int srow = l >> 2;
  const int skoff = (l & 3) * 8;
  const int lr = l & 15;
  const int kg = (l >> 4) * 8;
  const int rb0 = w * 16, rb1 = 64 + w * 16;

  const f16* gA0 = Abase + (size_t)(rb0 + srow) * LDA + skoff;
  const f16* gA1 = Abase + (size_t)(rb1 + srow) * LDA + skoff;
  const f16* gB0 = Bbase + (size_t)(rb0 + srow) * LDB + skoff;
  const f16* gB1 = Bbase + (size_t)(rb1 + srow) * LDB + skoff;

  const f16x8* rA0 = (const f16x8*)&As0[(wm * 64 + lr) * 32 + kg];
  const f16x8* rA1 = (const f16x8*)&As1[(wm * 64 + lr) * 32 + kg];
  const f16x8* rB0 = (const f16x8*)&Bs0[(wn * 64 + lr) * 32 + kg];
  const f16x8* rB1 = (const f16x8*)&Bs1[(wn * 64 + lr) * 32 + kg];

#define STAGE0() do { \
    gload_lds16(gA0, &As0[rb0 * 32]); gload_lds16(gA1, &As0[rb1 * 32]); \
    gload_lds16(gB0, &Bs0[rb0 * 32]); gload_lds16(gB1, &Bs0[rb1 * 32]); } while (0)
#define STAGE1() do { \
    gload_lds16(gA0, &As1[rb0 * 32]); gload_lds16(gA1, &As1[rb1 * 32]); \
    gload_lds16(gB0, &Bs1[rb0 * 32]); gload_lds16(gB1, &Bs1[rb1 * 32]); } while (0)
#define ADV() do { gA0 += 32; gA1 += 32; gB0 += 32; gB1 += 32; } while (0)
#define COMPUTE(rA, rB) do { \
    f16x8 av[4], bv[4]; \
    _Pragma("unroll") for (int m = 0; m < 4; ++m) av[m] = (rA)[m * 64]; \
    _Pragma("unroll") for (int n = 0; n < 4; ++n) bv[n] = (rB)[n * 64]; \
    _Pragma("unroll") for (int m = 0; m < 4; ++m) \
      _Pragma("unroll") for (int n = 0; n < 4; ++n) \
        acc[m][n] = __builtin_amdgcn_mfma_f32_16x16x32_f16(av[m], bv[n], acc[m][n], 0, 0, 0); \
  } while (0)

  STAGE0(); ADV();
  __syncthreads();
  for (int it = 0; it + 2 <= nk; it += 2) {
    STAGE1(); ADV();
    COMPUTE(rA0, rB0);
    __syncthreads();
    if (it + 2 < nk) { STAGE0(); }
    ADV();
    COMPUTE(rA1, rB1);
    __syncthreads();
  }
#undef STAGE0
#undef STAGE1
#undef ADV
#undef COMPUTE

  const int rg = (l >> 4) * 4;  // C/D: col = lane&15, row = (lane>>4)*4 + reg
  #pragma unroll
  for (int m = 0; m < 4; ++m) {
    #pragma unroll
    for (int n = 0; n < 4; ++n) {
      f32x4 v = acc[m][n];
      size_t coll = ccol0 + wn * 64 + n * 16 + lr;
      #pragma unroll
      for (int r = 0; r < 4; ++r) {
        size_t roww = crow0 + wm * 64 + m * 16 + rg + r;
        if constexpr (MODE == 2) {
          ((float*)C)[roww * cld + coll] = v[r];
        } else {
          ((f16*)C)[roww * cld + coll] = (f16)v[r];
        }
      }
    }
  }

  if constexpr (MODE == 2) {
    // per-(row, block) softmax partials: masked row max + sumexp -> Pstat
    __shared__ float smax_[2][128];
    __shared__ float ssum_[2][128];
    const int jbdiag = (q0 >> 7) + qb2;
    const bool below = (jb2 < jbdiag);
    float vm[4][4];
    #pragma unroll
    for (int m = 0; m < 4; ++m)
      #pragma unroll
      for (int r = 0; r < 4; ++r) {
        int rl = wm * 64 + m * 16 + rg + r;
        float best = -INFINITY;
        #pragma unroll
        for (int n = 0; n < 4; ++n) {
          int collL = wn * 64 + n * 16 + lr;
          if (below || collL <= rl) best = fmaxf(best, acc[m][n][r]);
        }
        vm[m][r] = best;
      }
    #pragma unroll
    for (int m = 0; m < 4; ++m)
      #pragma unroll
      for (int r = 0; r < 4; ++r)
        #pragma unroll
        for (int msk = 1; msk <= 8; msk <<= 1)
          vm[m][r] = fmaxf(vm[m][r], __shfl_xor(vm[m][r], msk));
    if ((l & 15) == 0) {
      #pragma unroll
      for (int m = 0; m < 4; ++m)
        #pragma unroll
        for (int r = 0; r < 4; ++r)
          smax_[wn][wm * 64 + m * 16 + rg + r] = vm[m][r];
    }
    __syncthreads();
    float Mv[4][4];
    #pragma unroll
    for (int m = 0; m < 4; ++m)
      #pragma unroll
      for (int r = 0; r < 4; ++r) {
        int rl = wm * 64 + m * 16 + rg + r;
        Mv[m][r] = fmaxf(smax_[0][rl], smax_[1][rl]);
      }
    #pragma unroll
    for (int m = 0; m < 4; ++m)
      #pragma unroll
      for (int r = 0; r < 4; ++r) {
        int rl = wm * 64 + m * 16 + rg + r;
        float s = 0.f;
        #pragma unroll
        for (int n = 0; n < 4; ++n) {
          int collL = wn * 64 + n * 16 + lr;
          if (below || collL <= rl) s += __expf(acc[m][n][r] - Mv[m][r]);
        }
        vm[m][r] = s;   // reuse
      }
    #pragma unroll
    for (int m = 0; m < 4; ++m)
      #pragma unroll
      for (int r = 0; r < 4; ++r)
        #pragma unroll
        for (int msk = 1; msk <= 8; msk <<= 1)
          vm[m][r] += __shfl_xor(vm[m][r], msk);
    if ((l & 15) == 0) {
      #pragma unroll
      for (int m = 0; m < 4; ++m)
        #pragma unroll
        for (int r = 0; r < 4; ++r)
          ssum_[wn][wm * 64 + m * 16 + rg + r] = vm[m][r];
    }
    __syncthreads();
    if ((l & 15) == 0 && wn == 0) {
      #pragma unroll
      for (int m = 0; m < 4; ++m)
        #pragma unroll
        for (int r = 0; r < 4; ++r) {
          int rl = wm * 64 + m * 16 + rg + r;
          float L = ssum_[0][rl] + ssum_[1][rl];
          Pstat[(crow0 + rl) * 64 + jb2] = make_float2(Mv[m][r], L);
        }
    }
  }
}

extern "C" void kernel_launch(void* const* d_in, const int* in_sizes, int n_in,
                              void* d_out, int out_size, void* d_ws, size_t ws_size,
                              hipStream_t stream) {
  (void)in_sizes; (void)n_in;
  const float* x      = (const float*)d_in[0];
  const float* w_attn = (const float*)d_in[1];
  const float* b_attn = (const float*)d_in[2];
  const float* w_proj = (const float*)d_in[3];
  const float* b_proj = (const float*)d_in[4];
  float* out = (float*)d_out;

  const size_t WS_NEED = 268173312ull;  // 255.75 MiB
  if (ws_size < WS_NEED) {
    fprintf(stderr, "kernel_launch: ws_size=%zu < needed %zu -- skipping launches\n",
            ws_size, WS_NEED);
    hipMemsetAsync(d_out, 0, (size_t)out_size * 4, stream);
    return;
  }

  char* p = (char*)d_ws;
  f16* wA_h = (f16*)p; p += (size_t)3072 * 1024 * 2;        //   6.3 MB
  f16* wP_h = (f16*)p; p += (size_t)1024 * 1024 * 2;        //   2.1 MB
  f16* qkv  = (f16*)p; p += (size_t)16384 * 3072 * 2;       // 100.7 MB
  f16* vt   = (f16*)p; p += (size_t)2 * 1024 * 8192 * 2;    //  33.6 MB
  f16* xo   = (f16*)p; p += (size_t)16384 * 1024 * 2;       //  33.6 MB (x_h, then o_h)
  float* S  = (float*)p; p += (size_t)2 * 3328 * 3328 * 4;  //  88.6 MB (scores; P in-place)
  float2* Pstat = (float2*)p; p += (size_t)2 * 3328 * 64 * 8; // 3.4 MB (row,block partials)
  // total 268,173,312 bytes

  k_cast<<<16384, 256, 0, stream>>>(x, xo, 4194304);
  k_cast<<<3072, 256, 0, stream>>>(w_attn, wA_h, 786432);
  k_cast<<<1024, 256, 0, stream>>>(w_proj, wP_h, 262144);
  hipLaunchKernelGGL(HIP_KERNEL_NAME(gemm_pipe<1>), dim3(3072), dim3(256), 0, stream,
                     xo, wA_h, (void*)qkv, b_attn);
  k_rope<<<4096, 256, 0, stream>>>(qkv);
  k_transpose<<<4096, 256, 0, stream>>>(qkv, vt);

  // 4 variable chunks equalizing S footprint
  const int Q0[4] = {0, 3328, 5376, 6912};
  const int Q1[4] = {3328, 5376, 6912, 8192};
  for (int c = 0; c < 4; ++c) {
    int q0 = Q0[c], q1 = Q1[c], R = q1 - q0;
    int nqt = R >> 7, ncb = q1 >> 7;
    hipLaunchKernelGGL(HIP_KERNEL_NAME(gemm_pp<2>), dim3(2 * nqt * ncb), dim3(256), 0, stream,
                       qkv, (const f16*)nullptr, (void*)S, Pstat, q0, q1);
    k_softmax_c<<<R / 2, 256, 0, stream>>>(S, Pstat, q0, q1);
    hipLaunchKernelGGL(HIP_KERNEL_NAME(gemm_pp<3>), dim3(2 * nqt * 8), dim3(256), 0, stream,
                       (const f16*)S, vt, (void*)xo, (float2*)nullptr, q0, q1);
  }
  hipLaunchKernelGGL(HIP_KERNEL_NAME(gemm_pipe<4>), dim3(1024), dim3(256), 0, stream,
                     xo, wP_h, (void*)out, b_proj);
}

// Round 14
// 1030.228 us; speedup vs baseline: 1.0868x; 1.0217x over previous
//
#include <hip/hip_runtime.h>
#include <hip/hip_fp16.h>
#include <cstdio>

typedef _Float16 f16;
typedef _Float16 f16x8 __attribute__((ext_vector_type(8)));
typedef _Float16 f16x4 __attribute__((ext_vector_type(4)));
typedef float f32x4 __attribute__((ext_vector_type(4)));

#define DI __device__ __forceinline__

DI void gload_lds16(const void* g, void* l) {
  __builtin_amdgcn_global_load_lds(
      (const __attribute__((address_space(1))) void*)g,
      (__attribute__((address_space(3))) void*)l, 16, 0, 0);
}

// XCD-aware block swizzle (bijective when gridDim.x % 8 == 0) [T1]
DI int xcd_swz() {
  int nwg = gridDim.x, bid = blockIdx.x;
  if ((nwg & 7) == 0) bid = (bid & 7) * (nwg >> 3) + (bid >> 3);
  return bid;
}

// ---------------- cast f32 -> f16, 4 elems/thread ----------------
__global__ void k_cast(const float* __restrict__ in, f16* __restrict__ out, int n4) {
  int i = blockIdx.x * blockDim.x + threadIdx.x;
  if (i >= n4) return;
  float4 v = ((const float4*)in)[i];
  f16x4 o;
  o[0] = (f16)v.x; o[1] = (f16)v.y; o[2] = (f16)v.z; o[3] = (f16)v.w;
  ((f16x4*)out)[i] = o;
}

// ---------------- RoPE in-place, vectorized: 8 pairs/thread ----------------
__global__ void k_rope(f16* __restrict__ qkv) {
  int gid = blockIdx.x * blockDim.x + threadIdx.x;  // 16384 * 64
  int tt = gid >> 6, j0 = (gid & 63) * 8;
  int t = tt & 8191;
  f16* row = qkv + (size_t)tt * 3072;
  f16x8 qa = *(f16x8*)(row + j0),        qb = *(f16x8*)(row + 512 + j0);
  f16x8 ka = *(f16x8*)(row + 1024 + j0), kb = *(f16x8*)(row + 1536 + j0);
  #pragma unroll
  for (int u = 0; u < 8; ++u) {
    int j = j0 + u;
    float invf = powf(10000.0f, -(float)j * (1.0f / 512.0f));
    float s, c;
    sincosf((float)t * invf, &s, &c);
    float q0v = (float)qa[u], q1v = (float)qb[u];
    qa[u] = (f16)(q0v * c - q1v * s); qb[u] = (f16)(q1v * c + q0v * s);
    float k0v = (float)ka[u], k1v = (float)kb[u];
    ka[u] = (f16)(k0v * c - k1v * s); kb[u] = (f16)(k1v * c + k0v * s);
  }
  *(f16x8*)(row + j0) = qa;        *(f16x8*)(row + 512 + j0) = qb;
  *(f16x8*)(row + 1024 + j0) = ka; *(f16x8*)(row + 1536 + j0) = kb;
}

// ---------------- V transpose: qkv[:,2048:3072] -> vt[b][d][t] ----------------
__global__ __launch_bounds__(256) void k_transpose(const f16* __restrict__ qkv, f16* __restrict__ vt) {
  __shared__ f16 tile[64][72];
  int bid = blockIdx.x;            // 2 * 128 * 16
  int b = bid >> 11;
  int rem = bid & 2047;
  int tb = (rem >> 4) * 64;        // token base
  int db = (rem & 15) * 64;        // d base
  int tid = threadIdx.x;
  int r = tid >> 2, c0 = (tid & 3) * 16;
  const f16* src = qkv + (size_t)(b * 8192 + tb + r) * 3072 + 2048 + db + c0;
  #pragma unroll
  for (int ii = 0; ii < 16; ++ii) tile[r][c0 + ii] = src[ii];
  __syncthreads();
  f16* dst = vt + (size_t)b * 1024 * 8192 + (size_t)(db + r) * 8192 + tb + c0;
  #pragma unroll
  for (int ii = 0; ii < 16; ++ii) dst[ii] = tile[c0 + ii][r];
}

// ---------------- chunk softmax: pass1 from Pstat partials, pass2 in-place S->P --
__global__ __launch_bounds__(256)
void k_softmax_c(float* __restrict__ S, const float2* __restrict__ Pstat, int q0, int q1) {
  int R = q1 - q0;
  int row = blockIdx.x * 4 + (threadIdx.x >> 6);  // 0..2R-1
  int lane = threadIdx.x & 63;
  int b = (row >= R) ? 1 : 0;
  int qloc = row - b * R;
  int qg = q0 + qloc;
  float* Srow = S + (size_t)row * q1;
  int nvalid = qg + 1;
  int djb = qg >> 7;                // last valid 128-col block for this row

  float2 st = make_float2(-INFINITY, 0.f);
  if (lane <= djb) st = Pstat[(size_t)row * 64 + lane];
  float m = st.x;
  #pragma unroll
  for (int msk = 32; msk >= 1; msk >>= 1) m = fmaxf(m, __shfl_xor(m, msk));
  float contrib = (lane <= djb) ? st.y * __expf(st.x - m) : 0.f;
  #pragma unroll
  for (int msk = 32; msk >= 1; msk >>= 1) contrib += __shfl_xor(contrib, msk);
  float ssum = contrib;

  float rinv = 0.03125f / ssum;  // 1024^-0.5 applied post-softmax (reference quirk)
  int klim = (qg | 127) + 1;     // zero-fill to PV's k-tile boundary
  f16* Prow = (f16*)Srow;
  for (int kk = lane * 4; kk < klim; kk += 256) {
    float4 v = *(const float4*)(Srow + kk);
    asm volatile("" ::: "memory");  // keep f32 load before aliasing f16 store
    f16x4 o;
    o[0] = (f16)((kk     < nvalid) ? __expf(v.x - m) * rinv : 0.f);
    o[1] = (f16)((kk + 1 < nvalid) ? __expf(v.y - m) * rinv : 0.f);
    o[2] = (f16)((kk + 2 < nvalid) ? __expf(v.z - m) * rinv : 0.f);
    o[3] = (f16)((kk + 3 < nvalid) ? __expf(v.w - m) * rinv : 0.f);
    *(f16x4*)(Prow + kk) = o;
  }
}

// ==== gemm_256: 256x256 tile, 8 waves, BK=32, ring-4 LDS, counted vmcnt [T3/T4] ====
// Schedule per window (r11-proven shape): STAGE(tile i+2 -> slot (i+2)&3);
// s_waitcnt vmcnt(8) [commits tile i, 2 tiles stay in flight]; s_barrier;
// COMPUTE(slot i&3). Ring-4 skew safety: stage slot never equals any slot
// readable by a wave <=1 window behind (4 does not divide 2 or 3).
// MODE 1: qkv = x_h @ w_attn^T + b  (M=16384,N=3072) -> fp16, L2-grouped 4bm x 2bn
// MODE 4: out = o @ w_proj^T + b    (M=16384,N=1024) -> fp32
template <int MODE>
__global__ __launch_bounds__(512)
void gemm_256(const f16* __restrict__ A, const f16* __restrict__ B,
              void* __restrict__ C, const float* __restrict__ bias)
{
  __shared__ __align__(16) f16 As[4][8192];   // 4 slots x 256x32 f16 = 64 KB
  __shared__ __align__(16) f16 Bs[4][8192];   // 64 KB (total 128 KB, 1 block/CU)

  const int tid = threadIdx.x;
  const int w = tid >> 6;          // 0..7
  const int l = tid & 63;
  const int wm = w >> 2;           // 0..1 : 128-row half
  const int wn = w & 3;            // 0..3 : 64-col quarter
  const int bid = xcd_swz();

  int bm, bn;
  if constexpr (MODE == 1) {
    int grp = bid >> 3, off = bid & 7;   // 96 groups of 8 blocks (4bm x 2bn)
    bm = (grp / 6) * 4 + (off >> 1);
    bn = (grp % 6) * 2 + (off & 1);
  } else {
    bm = bid >> 2; bn = bid & 3;
  }
  const int nk = 32;
  const f16* Abase = A + (size_t)bm * 256 * 1024;
  const f16* Bbase = B + (size_t)bn * 256 * 1024;

  f32x4 acc[8][4];
  #pragma unroll
  for (int m = 0; m < 8; ++m)
    #pragma unroll
    for (int n = 0; n < 4; ++n) { acc[m][n][0]=0.f; acc[m][n][1]=0.f; acc[m][n][2]=0.f; acc[m][n][3]=0.f; }

  // staging: thread loads 16B at row = rnd*128 + (tid>>2), col = t*32 + (tid&3)*8
  const int srow = tid >> 2;
  const int scol = (tid & 3) * 8;
  const f16* gA0 = Abase + (size_t)srow * 1024 + scol;
  const f16* gA1 = gA0 + (size_t)128 * 1024;
  const f16* gB0 = Bbase + (size_t)srow * 1024 + scol;
  const f16* gB1 = gB0 + (size_t)128 * 1024;
  const int ldst = tid * 8;                 // LDS dest elem offset within a round

  // fragment reads: lane l, m-frag mf: A row wm*128+mf*16+(l&15), k (l>>4)*8
  const int aoffb = (wm * 128 + (l & 15)) * 32 + (l >> 4) * 8;
  const int boffb = (wn * 64 + (l & 15)) * 32 + (l >> 4) * 8;

#define STAGE(slot, t) do { \
    const size_t _o = (size_t)(t) * 32; \
    f16* _as = As[slot]; f16* _bs = Bs[slot]; \
    gload_lds16(gA0 + _o, _as + ldst); \
    gload_lds16(gA1 + _o, _as + 4096 + ldst); \
    gload_lds16(gB0 + _o, _bs + ldst); \
    gload_lds16(gB1 + _o, _bs + 4096 + ldst); } while (0)
#define COMPUTE(slot) do { \
    const f16* pa = As[slot] + aoffb; \
    const f16* pb = Bs[slot] + boffb; \
    f16x8 av[8], bv[4]; \
    _Pragma("unroll") for (int m = 0; m < 8; ++m) av[m] = *(const f16x8*)(pa + m * 512); \
    _Pragma("unroll") for (int n = 0; n < 4; ++n) bv[n] = *(const f16x8*)(pb + n * 512); \
    _Pragma("unroll") for (int m = 0; m < 8; ++m) \
      _Pragma("unroll") for (int n = 0; n < 4; ++n) \
        acc[m][n] = __builtin_amdgcn_mfma_f32_16x16x32_f16(av[m], bv[n], acc[m][n], 0, 0, 0); \
  } while (0)

  // prologue: tiles 0,1 in flight (8 loads/wave)
  STAGE(0, 0); STAGE(1, 1);
  for (int i = 0; i < nk; ++i) {
    int ts = (i + 2 < nk) ? i + 2 : nk - 1;   // clamped tail (r11-proven)
    STAGE((i + 2) & 3, ts);
    asm volatile("s_waitcnt vmcnt(8)" ::: "memory");  // commit tile i
    __builtin_amdgcn_s_barrier();
    COMPUTE(i & 3);
  }
#undef STAGE
#undef COMPUTE

  const int rg = (l >> 4) * 4;  // C/D: col = lane&15, row = (lane>>4)*4 + reg
  #pragma unroll
  for (int m = 0; m < 8; ++m) {
    #pragma unroll
    for (int n = 0; n < 4; ++n) {
      f32x4 v = acc[m][n];
      size_t coll = (size_t)bn * 256 + wn * 64 + n * 16 + (l & 15);
      #pragma unroll
      for (int r = 0; r < 4; ++r) {
        size_t roww = (size_t)bm * 256 + wm * 128 + m * 16 + rg + r;
        if constexpr (MODE == 1) {
          ((f16*)C)[roww * 3072 + coll] = (f16)(v[r] + bias[coll]);
        } else {
          ((float*)C)[roww * 1024 + coll] = v[r] + bias[coll];
        }
      }
    }
  }
}

// ==== gemm_pp: r10 ping-pong engine (2-phase, 32 KB LDS, high occupancy) ====
// MODE 2: S[2R][q1] = q @ k^T  + per-(row,block) (max,sumexp) -> Pstat
// MODE 3: xo = P @ vt^T        (P in-place in S, lda=2*q1)    -> fp16
template <int MODE>
__global__ __launch_bounds__(256)
void gemm_pp(const f16* __restrict__ A, const f16* __restrict__ B,
             void* __restrict__ C, float2* __restrict__ Pstat, int q0, int q1)
{
  __shared__ __align__(16) f16 As0[128 * 32];
  __shared__ __align__(16) f16 As1[128 * 32];
  __shared__ __align__(16) f16 Bs0[128 * 32];
  __shared__ __align__(16) f16 Bs1[128 * 32];

  const int tid = threadIdx.x;
  const int w = tid >> 6;
  const int l = tid & 63;
  const int wm = w >> 1, wn = w & 1;
  const int bid = xcd_swz();
  const int R = q1 - q0;

  int nk = 0, qb2 = 0, jb2 = 0;
  const f16* Abase = nullptr;
  const f16* Bbase = nullptr;
  size_t crow0 = 0, ccol0 = 0, cld = 0;
  const int LDA = (MODE == 2) ? 3072 : 2 * q1;
  const int LDB = (MODE == 2) ? 3072 : 8192;

  if constexpr (MODE == 2) {
    int nqt = R >> 7, ncb = q1 >> 7;
    int b = bid / (nqt * ncb);
    int rem = bid % (nqt * ncb);
    qb2 = rem / ncb; jb2 = rem % ncb;
    if (jb2 > (q0 >> 7) + qb2) return;   // fully-masked (uniform exit, pre-barrier)
    Abase = A + (size_t)(b * 8192 + q0 + qb2 * 128) * 3072;
    Bbase = A + (size_t)(b * 8192 + jb2 * 128) * 3072 + 1024;
    nk = 32;
    crow0 = (size_t)(b * R + qb2 * 128); ccol0 = (size_t)jb2 * 128; cld = q1;
  } else {
    int nqt = R >> 7;
    int b = bid / (nqt * 8);
    int rem = bid % (nqt * 8);
    int qb = rem / 8, nb = rem % 8;
    nk = ((q0 >> 7) + qb + 1) * 4;       // even
    Abase = A + (size_t)(b * R + qb * 128) * 2 * q1;   // P in-place in S
    Bbase = B + (size_t)b * 1024 * 8192 + (size_t)nb * 128 * 8192;
    crow0 = (size_t)(b * 8192 + q0 + qb * 128); ccol0 = (size_t)nb * 128; cld = 1024;
  }

  f32x4 zero = {0.f, 0.f, 0.f, 0.f};
  f32x4 acc[4][4];
  #pragma unroll
  for (int m = 0; m < 4; ++m)
    #pragma unroll
    for (int n = 0; n < 4; ++n) acc[m][n] = zero;

  const int srow = l >> 2;
  const int skoff = (l & 3) * 8;
  const int lr = l & 15;
  const int kg = (l >> 4) * 8;
  const int rb0 = w * 16, rb1 = 64 + w * 16;

  const f16* gA0 = Abase + (size_t)(rb0 + srow) * LDA + skoff;
  const f16* gA1 = Abase + (size_t)(rb1 + srow) * LDA + skoff;
  const f16* gB0 = Bbase + (size_t)(rb0 + srow) * LDB + skoff;
  const f16* gB1 = Bbase + (size_t)(rb1 + srow) * LDB + skoff;

  const f16x8* rA0 = (const f16x8*)&As0[(wm * 64 + lr) * 32 + kg];
  const f16x8* rA1 = (const f16x8*)&As1[(wm * 64 + lr) * 32 + kg];
  const f16x8* rB0 = (const f16x8*)&Bs0[(wn * 64 + lr) * 32 + kg];
  const f16x8* rB1 = (const f16x8*)&Bs1[(wn * 64 + lr) * 32 + kg];

#define STAGE0() do { \
    gload_lds16(gA0, &As0[rb0 * 32]); gload_lds16(gA1, &As0[rb1 * 32]); \
    gload_lds16(gB0, &Bs0[rb0 * 32]); gload_lds16(gB1, &Bs0[rb1 * 32]); } while (0)
#define STAGE1() do { \
    gload_lds16(gA0, &As1[rb0 * 32]); gload_lds16(gA1, &As1[rb1 * 32]); \
    gload_lds16(gB0, &Bs1[rb0 * 32]); gload_lds16(gB1, &Bs1[rb1 * 32]); } while (0)
#define ADV() do { gA0 += 32; gA1 += 32; gB0 += 32; gB1 += 32; } while (0)
#define COMPUTE(rA, rB) do { \
    f16x8 av[4], bv[4]; \
    _Pragma("unroll") for (int m = 0; m < 4; ++m) av[m] = (rA)[m * 64]; \
    _Pragma("unroll") for (int n = 0; n < 4; ++n) bv[n] = (rB)[n * 64]; \
    _Pragma("unroll") for (int m = 0; m < 4; ++m) \
      _Pragma("unroll") for (int n = 0; n < 4; ++n) \
        acc[m][n] = __builtin_amdgcn_mfma_f32_16x16x32_f16(av[m], bv[n], acc[m][n], 0, 0, 0); \
  } while (0)

  STAGE0(); ADV();
  __syncthreads();
  for (int it = 0; it + 2 <= nk; it += 2) {
    STAGE1(); ADV();
    COMPUTE(rA0, rB0);
    __syncthreads();
    if (it + 2 < nk) { STAGE0(); }
    ADV();
    COMPUTE(rA1, rB1);
    __syncthreads();
  }
#undef STAGE0
#undef STAGE1
#undef ADV
#undef COMPUTE

  const int rg = (l >> 4) * 4;  // C/D: col = lane&15, row = (lane>>4)*4 + reg
  #pragma unroll
  for (int m = 0; m < 4; ++m) {
    #pragma unroll
    for (int n = 0; n < 4; ++n) {
      f32x4 v = acc[m][n];
      size_t coll = ccol0 + wn * 64 + n * 16 + lr;
      #pragma unroll
      for (int r = 0; r < 4; ++r) {
        size_t roww = crow0 + wm * 64 + m * 16 + rg + r;
        if constexpr (MODE == 2) {
          ((float*)C)[roww * cld + coll] = v[r];
        } else {
          ((f16*)C)[roww * cld + coll] = (f16)v[r];
        }
      }
    }
  }

  if constexpr (MODE == 2) {
    // per-(row, block) softmax partials: masked row max + sumexp -> Pstat
    __shared__ float smax_[2][128];
    __shared__ float ssum_[2][128];
    const int jbdiag = (q0 >> 7) + qb2;
    const bool below = (jb2 < jbdiag);
    float vm[4][4];
    #pragma unroll
    for (int m = 0; m < 4; ++m)
      #pragma unroll
      for (int r = 0; r < 4; ++r) {
        int rl = wm * 64 + m * 16 + rg + r;
        float best = -INFINITY;
        #pragma unroll
        for (int n = 0; n < 4; ++n) {
          int collL = wn * 64 + n * 16 + lr;
          if (below || collL <= rl) best = fmaxf(best, acc[m][n][r]);
        }
        vm[m][r] = best;
      }
    #pragma unroll
    for (int m = 0; m < 4; ++m)
      #pragma unroll
      for (int r = 0; r < 4; ++r)
        #pragma unroll
        for (int msk = 1; msk <= 8; msk <<= 1)
          vm[m][r] = fmaxf(vm[m][r], __shfl_xor(vm[m][r], msk));
    if ((l & 15) == 0) {
      #pragma unroll
      for (int m = 0; m < 4; ++m)
        #pragma unroll
        for (int r = 0; r < 4; ++r)
          smax_[wn][wm * 64 + m * 16 + rg + r] = vm[m][r];
    }
    __syncthreads();
    float Mv[4][4];
    #pragma unroll
    for (int m = 0; m < 4; ++m)
      #pragma unroll
      for (int r = 0; r < 4; ++r) {
        int rl = wm * 64 + m * 16 + rg + r;
        Mv[m][r] = fmaxf(smax_[0][rl], smax_[1][rl]);
      }
    #pragma unroll
    for (int m = 0; m < 4; ++m)
      #pragma unroll
      for (int r = 0; r < 4; ++r) {
        int rl = wm * 64 + m * 16 + rg + r;
        float s = 0.f;
        #pragma unroll
        for (int n = 0; n < 4; ++n) {
          int collL = wn * 64 + n * 16 + lr;
          if (below || collL <= rl) s += __expf(acc[m][n][r] - Mv[m][r]);
        }
        vm[m][r] = s;   // reuse
      }
    #pragma unroll
    for (int m = 0; m < 4; ++m)
      #pragma unroll
      for (int r = 0; r < 4; ++r)
        #pragma unroll
        for (int msk = 1; msk <= 8; msk <<= 1)
          vm[m][r] += __shfl_xor(vm[m][r], msk);
    if ((l & 15) == 0) {
      #pragma unroll
      for (int m = 0; m < 4; ++m)
        #pragma unroll
        for (int r = 0; r < 4; ++r)
          ssum_[wn][wm * 64 + m * 16 + rg + r] = vm[m][r];
    }
    __syncthreads();
    if ((l & 15) == 0 && wn == 0) {
      #pragma unroll
      for (int m = 0; m < 4; ++m)
        #pragma unroll
        for (int r = 0; r < 4; ++r) {
          int rl = wm * 64 + m * 16 + rg + r;
          float L = ssum_[0][rl] + ssum_[1][rl];
          Pstat[(crow0 + rl) * 64 + jb2] = make_float2(Mv[m][r], L);
        }
    }
  }
}

extern "C" void kernel_launch(void* const* d_in, const int* in_sizes, int n_in,
                              void* d_out, int out_size, void* d_ws, size_t ws_size,
                              hipStream_t stream) {
  (void)in_sizes; (void)n_in;
  const float* x      = (const float*)d_in[0];
  const float* w_attn = (const float*)d_in[1];
  const float* b_attn = (const float*)d_in[2];
  const float* w_proj = (const float*)d_in[3];
  const float* b_proj = (const float*)d_in[4];
  float* out = (float*)d_out;

  const size_t WS_NEED = 268173312ull;  // 255.75 MiB
  if (ws_size < WS_NEED) {
    fprintf(stderr, "kernel_launch: ws_size=%zu < needed %zu -- skipping launches\n",
            ws_size, WS_NEED);
    hipMemsetAsync(d_out, 0, (size_t)out_size * 4, stream);
    return;
  }

  char* p = (char*)d_ws;
  f16* wA_h = (f16*)p; p += (size_t)3072 * 1024 * 2;        //   6.3 MB
  f16* wP_h = (f16*)p; p += (size_t)1024 * 1024 * 2;        //   2.1 MB
  f16* qkv  = (f16*)p; p += (size_t)16384 * 3072 * 2;       // 100.7 MB
  f16* vt   = (f16*)p; p += (size_t)2 * 1024 * 8192 * 2;    //  33.6 MB
  f16* xo   = (f16*)p; p += (size_t)16384 * 1024 * 2;       //  33.6 MB (x_h, then o_h)
  float* S  = (float*)p; p += (size_t)2 * 3328 * 3328 * 4;  //  88.6 MB (scores; P in-place)
  float2* Pstat = (float2*)p; p += (size_t)2 * 3328 * 64 * 8; // 3.4 MB (row,block partials)
  // total 268,173,312 bytes

  k_cast<<<16384, 256, 0, stream>>>(x, xo, 4194304);
  k_cast<<<3072, 256, 0, stream>>>(w_attn, wA_h, 786432);
  k_cast<<<1024, 256, 0, stream>>>(w_proj, wP_h, 262144);
  hipLaunchKernelGGL(HIP_KERNEL_NAME(gemm_256<1>), dim3(768), dim3(512), 0, stream,
                     xo, wA_h, (void*)qkv, b_attn);
  k_rope<<<4096, 256, 0, stream>>>(qkv);
  k_transpose<<<4096, 256, 0, stream>>>(qkv, vt);

  // 4 variable chunks equalizing S footprint
  const int Q0[4] = {0, 3328, 5376, 6912};
  const int Q1[4] = {3328, 5376, 6912, 8192};
  for (int c = 0; c < 4; ++c) {
    int q0 = Q0[c], q1 = Q1[c], R = q1 - q0;
    int nqt = R >> 7, ncb = q1 >> 7;
    hipLaunchKernelGGL(HIP_KERNEL_NAME(gemm_pp<2>), dim3(2 * nqt * ncb), dim3(256), 0, stream,
                       qkv, (const f16*)nullptr, (void*)S, Pstat, q0, q1);
    k_softmax_c<<<R / 2, 256, 0, stream>>>(S, Pstat, q0, q1);
    hipLaunchKernelGGL(HIP_KERNEL_NAME(gemm_pp<3>), dim3(2 * nqt * 8), dim3(256), 0, stream,
                       (const f16*)S, vt, (void*)xo, (float2*)nullptr, q0, q1);
  }
  hipLaunchKernelGGL(HIP_KERNEL_NAME(gemm_256<4>), dim3(256), dim3(512), 0, stream,
                     xo, wP_h, (void*)out, b_proj);
}